// Round 1
// baseline (79.533 us; speedup 1.0000x reference)
//
#include <hip/hip_runtime.h>

#define N_CELLS   16384
#define N_CLASSES 64
#define BATCH     64

__device__ __forceinline__ float agm_act(float s) {
    // 1.7159 * tanh((2/3)*s), computed as sign-safe rational exp form
    float z  = 0.66666666667f * s;
    float az = fabsf(z);
    float e  = __expf(-2.0f * az);          // in (0,1], no overflow
    float t  = (1.0f - e) / (1.0f + e);     // tanh(|z|)
    return copysignf(1.7159f * t, z);
}

__global__ __launch_bounds__(256) void mnl_kernel(
    const float* __restrict__ x,     // (B, N)   [inner dim 1 dropped]
    const float* __restrict__ w,     // (N, C, 3)
    const float* __restrict__ bias,  // (N, C)
    float* __restrict__ out)         // (B, N, C)
{
    const int i  = blockIdx.x;           // cell index
    const int t  = threadIdx.x;
    const int c4 = (t & 15) * 4;         // class group: 4 consecutive classes
    const int b0 = t >> 4;               // 0..15, batch lane within block

    const int il = (i == 0)           ? N_CELLS - 1 : i - 1;
    const int ir = (i == N_CELLS - 1) ? 0           : i + 1;

    // ---- weights for 4 classes: 12 consecutive floats, 16B-aligned ----
    const float4* wv = reinterpret_cast<const float4*>(
        w + (size_t)i * (N_CLASSES * 3) + (size_t)c4 * 3);
    float4 v0 = wv[0], v1 = wv[1], v2 = wv[2];
    float wr[12] = { v0.x, v0.y, v0.z, v0.w,
                     v1.x, v1.y, v1.z, v1.w,
                     v2.x, v2.y, v2.z, v2.w };
    // class j (0..3): w0 = wr[3j], w1 = wr[3j+1], w2 = wr[3j+2]

    const float4 bi = *reinterpret_cast<const float4*>(
        bias + (size_t)i * N_CLASSES + c4);
    const float bj[4] = { bi.x, bi.y, bi.z, bi.w };

    #pragma unroll
    for (int p = 0; p < 4; ++p) {
        const int b = p * 16 + b0;
        const float xl = x[(size_t)b * N_CELLS + il];
        const float xc = x[(size_t)b * N_CELLS + i];
        const float xr = x[(size_t)b * N_CELLS + ir];

        float4 o;
        {
            float s0 = fmaf(xl, wr[0], fmaf(xc, wr[1], fmaf(xr, wr[2],  bj[0])));
            float s1 = fmaf(xl, wr[3], fmaf(xc, wr[4], fmaf(xr, wr[5],  bj[1])));
            float s2 = fmaf(xl, wr[6], fmaf(xc, wr[7], fmaf(xr, wr[8],  bj[2])));
            float s3 = fmaf(xl, wr[9], fmaf(xc, wr[10],fmaf(xr, wr[11], bj[3])));
            o.x = agm_act(s0);
            o.y = agm_act(s1);
            o.z = agm_act(s2);
            o.w = agm_act(s3);
        }

        float4* op = reinterpret_cast<float4*>(
            out + ((size_t)b * N_CELLS + i) * N_CLASSES + c4);
        *op = o;
    }
}

extern "C" void kernel_launch(void* const* d_in, const int* in_sizes, int n_in,
                              void* d_out, int out_size, void* d_ws, size_t ws_size,
                              hipStream_t stream) {
    const float* x    = (const float*)d_in[0];  // (64, 16384, 1)
    const float* w    = (const float*)d_in[1];  // (16384, 64, 3)
    const float* bias = (const float*)d_in[2];  // (16384, 64)
    float* out = (float*)d_out;                 // (64, 16384, 64)

    dim3 grid(N_CELLS);
    dim3 block(256);
    mnl_kernel<<<grid, block, 0, stream>>>(x, w, bias, out);
}

// Round 3
// 56.838 us; speedup vs baseline: 1.3993x; 1.3993x over previous
//
#include <hip/hip_runtime.h>

#define N_CELLS   16384
#define N_CLASSES 64
#define BATCH     64
#define CPB       4   // cells per block

typedef float f32x4 __attribute__((ext_vector_type(4)));

// 1.7159 * tanh((2/3)*s)  — sign-safe fast form.
// tanh(z) = (1-e)/(1+e) with e = exp(-2z); z = (2/3)|s| -> e = exp(-(4/3)|s|)
__device__ __forceinline__ float agm_act(float s) {
    float az = fabsf(s);
    float e  = __expf(-1.3333333333f * az);      // in (0,1], no overflow
    float t  = __fdividef(1.0f - e, 1.0f + e);   // rcp + mul, ~1 ulp
    return copysignf(1.7159f * t, s);
}

__global__ __launch_bounds__(256) void mnl_kernel(
    const float* __restrict__ x,     // (B, N)
    const float* __restrict__ w,     // (N, C, 3)
    const float* __restrict__ bias,  // (N, C)
    float* __restrict__ out)         // (B, N, C)
{
    const int t    = threadIdx.x;
    const int lane = t & 63;
    const int wid  = t >> 6;              // wave id 0..3 -> batch phase
    const int di   = lane >> 4;           // cell within block, 0..3
    const int c4   = (lane & 15) * 4;     // class group
    const int i    = blockIdx.x * CPB + di;

    const int il = (i == 0)           ? N_CELLS - 1 : i - 1;
    const int ir = (i == N_CELLS - 1) ? 0           : i + 1;

    // ---- per-thread weights: 12 consecutive floats (16B aligned) ----
    const float4* wv = reinterpret_cast<const float4*>(
        w + (size_t)i * (N_CLASSES * 3) + (size_t)c4 * 3);
    const float4 v0 = wv[0], v1 = wv[1], v2 = wv[2];
    const float wr[12] = { v0.x, v0.y, v0.z, v0.w,
                           v1.x, v1.y, v1.z, v1.w,
                           v2.x, v2.y, v2.z, v2.w };

    const float4 bi = *reinterpret_cast<const float4*>(
        bias + (size_t)i * N_CLASSES + c4);
    const float bj[4] = { bi.x, bi.y, bi.z, bi.w };

    // wave-contiguous store: lanes cover 1KB (4 cells x 64 classes)
    // out float offset = (b*N + i)*C + c4
    #pragma unroll 4
    for (int p = 0; p < 16; ++p) {
        const int b = p * 4 + wid;
        const size_t xb = (size_t)b * N_CELLS;

        const float xl = x[xb + il];
        const float xc = x[xb + i];
        const float xr = x[xb + ir];

        f32x4 o;
        o.x = agm_act(fmaf(xl, wr[0], fmaf(xc, wr[1],  fmaf(xr, wr[2],  bj[0]))));
        o.y = agm_act(fmaf(xl, wr[3], fmaf(xc, wr[4],  fmaf(xr, wr[5],  bj[1]))));
        o.z = agm_act(fmaf(xl, wr[6], fmaf(xc, wr[7],  fmaf(xr, wr[8],  bj[2]))));
        o.w = agm_act(fmaf(xl, wr[9], fmaf(xc, wr[10], fmaf(xr, wr[11], bj[3]))));

        f32x4* op = reinterpret_cast<f32x4*>(
            out + ((size_t)b * N_CELLS + i) * N_CLASSES + c4);
        __builtin_nontemporal_store(o, op);
    }
}

extern "C" void kernel_launch(void* const* d_in, const int* in_sizes, int n_in,
                              void* d_out, int out_size, void* d_ws, size_t ws_size,
                              hipStream_t stream) {
    const float* x    = (const float*)d_in[0];  // (64, 16384, 1)
    const float* w    = (const float*)d_in[1];  // (16384, 64, 3)
    const float* bias = (const float*)d_in[2];  // (16384, 64)
    float* out = (float*)d_out;                 // (64, 16384, 64)

    dim3 grid(N_CELLS / CPB);
    dim3 block(256);
    mnl_kernel<<<grid, block, 0, stream>>>(x, w, bias, out);
}